// Round 1
// baseline (131.388 us; speedup 1.0000x reference)
//
#include <hip/hip_runtime.h>

// ---------------------------------------------------------------------------
// SocialPooling: pooled = per-person 8x8-grid scatter-add of neighbor hiddens,
// out = relu(pooled @ W + b).  M=B=4096, K=4096, N=1024.
// R10: GEMM wave arrangement 2m x 2n -> 2m x 2k (K-split).  Wave tile grows
// 64x32 -> 64x64 (4 MFMA per 4 KB of ds_read = 32 FLOP/LDS-byte vs 21.3), A
// read-amplification 2x -> 1x.  Block LDS reads/K-step: 96 KB -> 64 KB
// (kernel measured at the ds_read_b128 BW roofline, ~76 B/cyc/CU).  K-half
// partials reduced through As (32 KB f32) in the epilogue.  Staging, swizzle,
// XCD mapping, grid 512, occupancy all unchanged from R9.  Prep unchanged.
// ---------------------------------------------------------------------------

#define BM 128
#define BN 64
#define BK 128   // shorts (bf16) per K-block

typedef short short8 __attribute__((ext_vector_type(8)));
typedef short short4v __attribute__((ext_vector_type(4)));
typedef float floatx16 __attribute__((ext_vector_type(16)));

__device__ inline short f2bf(float x) {
    union { float f; unsigned u; } v; v.f = x;
    unsigned r = v.u + 0x7fffu + ((v.u >> 16) & 1u);   // round-to-nearest-even
    return (short)(r >> 16);
}

__device__ inline void gload_lds16(const void* g, void* l) {
    __builtin_amdgcn_global_load_lds(
        (const __attribute__((address_space(1))) void*)g,
        (__attribute__((address_space(3))) void*)l,
        16, 0, 0);
}

// ---------------------------------------------------------------------------
// Kernel 1: prep = pool (blocks 0..1023) + W transpose/cast (blocks 1024..2047)
// merged so the two independent stages run concurrently.  (unchanged)
// ---------------------------------------------------------------------------
__global__ __launch_bounds__(256) void prep_kernel(
    const float* __restrict__ h,     // (B, 64)
    const float* __restrict__ pos,   // (B, 2)
    short* __restrict__ pooled,      // (B, 4096) bf16
    const float* __restrict__ W,     // (K, N)
    short* __restrict__ Wt,          // (N, K) bf16
    int K, int N, int poolBlocks)
{
    __shared__ __align__(16) unsigned char sh[18944];
    const int tid = threadIdx.x;

    if ((int)blockIdx.x < poolBlocks) {
        // ----- pooling: 4 persons of one sequence per block -----
        float* hs = (float*)sh;                          // 64*64 f32 = 16 KB
        float* px = (float*)(sh + 16384);
        float* py = (float*)(sh + 16640);
        unsigned long long* wmask = (unsigned long long*)(sh + 16896); // 4*64

        const int lane = tid & 63;
        const int w    = tid >> 6;
        const int s    = blockIdx.x >> 4;
        const int grp  = blockIdx.x & 15;
        const size_t base = (size_t)s * 64;

        const float4* hv  = (const float4*)(h + base * 64);
        float4*       hsv = (float4*)hs;
        #pragma unroll
        for (int c = 0; c < 4; ++c) hsv[tid + c * 256] = hv[tid + c * 256];
        if (tid < 64) {
            float2 p = ((const float2*)pos)[base + tid];
            px[tid] = p.x; py[tid] = p.y;
        }
        wmask[w * 64 + lane] = 0ull;
        __syncthreads();

        const int i = grp * 4 + w;
        const float tlx = px[i] - 1.0f;
        const float tly = py[i] + 1.0f;
        const float brx = px[i] + 1.0f;
        const float bry = py[i] - 1.0f;

        {   // lane j: neighbor j's cell for person i (wave-local)
            const int j = lane;
            const float ox = px[j], oy = py[j];
            if (ox < brx && ox > tlx && oy < tly && oy > bry && j != i) {
                int cx = (int)floorf((ox - tlx) * 4.0f);
                int cy = (int)floorf((tly - oy) * 4.0f);
                atomicOr(&wmask[w * 64 + cx + cy * 8], 1ull << j);
            }
        }

        // phase C: 2 cells per wave-pass; lane half picks the cell, each lane
        // sums a float2 dim-pair.
        const int half = lane >> 5;            // cell offset 0/1
        const int d0   = (lane & 31) * 2;      // dim pair
        const size_t orow = (base + i) * 4096;
        unsigned short* pooledU = (unsigned short*)pooled;
        for (int c = 0; c < 64; c += 2) {
            unsigned long long m = wmask[w * 64 + c + half];
            float ax = 0.f, ay = 0.f;
            while (m) {
                int j0 = __builtin_ctzll(m); m &= m - 1;
                float2 hv2 = *(const float2*)&hs[j0 * 64 + d0];
                ax += hv2.x; ay += hv2.y;
            }
            unsigned pk = ((unsigned)(unsigned short)f2bf(ay) << 16)
                        |  (unsigned short)f2bf(ax);
            *(unsigned*)&pooledU[orow + (size_t)(c + half) * 64 + d0] = pk;
        }
    } else {
        // ----- W (K x N f32) -> Wt (N x K bf16), 64x64 tiles -----
        float* t = (float*)sh;                 // [64][65]
        const int bid = blockIdx.x - poolBlocks;
        const int k0 = (bid & 63) * 64;
        const int n0 = (bid >> 6) * 64;

        const int r  = tid >> 4;               // 0..15
        const int cq = (tid & 15) * 4;
        #pragma unroll
        for (int i2 = 0; i2 < 4; ++i2) {
            const int row = r + i2 * 16;
            float4 v = *(const float4*)&W[(size_t)(k0 + row) * N + n0 + cq];
            t[row * 65 + cq + 0] = v.x; t[row * 65 + cq + 1] = v.y;
            t[row * 65 + cq + 2] = v.z; t[row * 65 + cq + 3] = v.w;
        }
        __syncthreads();
        const int nl = tid >> 4;
        const int kq = (tid & 15) * 4;
        #pragma unroll
        for (int i2 = 0; i2 < 4; ++i2) {
            const int n = nl + i2 * 16;
            short4v o;
            o.x = f2bf(t[(kq + 0) * 65 + n]); o.y = f2bf(t[(kq + 1) * 65 + n]);
            o.z = f2bf(t[(kq + 2) * 65 + n]); o.w = f2bf(t[(kq + 3) * 65 + n]);
            *(short4v*)&Wt[(size_t)(n0 + n) * K + k0 + kq] = o;
        }
    }
}

// ---------------------------------------------------------------------------
// Kernel 2: C = relu(A @ Bt^T + bias).  A: MxK, Bt: NxK bf16.
// 128x64 block tile, BK=128, 4 waves arranged 2m x 2k: wave (wr, kh) computes
// the full 64x64 output tile for its m-half over its K-half.  Per t-step:
// 4 ds_read_b128 feed 4 MFMAs (32 FLOP/LDS-byte).  K-half partials reduced
// through As (reused as 2x64x64 f32) before bias+relu+store.
// ---------------------------------------------------------------------------
__global__ __launch_bounds__(256) void gemm_bias_relu(
    const short* __restrict__ A,
    const short* __restrict__ Bt,
    const float* __restrict__ bias,
    float* __restrict__ out,
    int M, int N, int K)
{
    __shared__ __align__(16) short As[BM * BK];  // 32 KB
    __shared__ __align__(16) short Bs[BN * BK];  // 16 KB

    const int tid  = threadIdx.x;
    const int lane = tid & 63;
    const int wave = tid >> 6;
    const int wr = wave >> 1;          // wave m-half: 0..1
    const int kh = wave & 1;           // wave K-half: 0..1
    const int nl = lane & 31;          // MFMA row/col within 32
    const int hl = lane >> 5;          // K-half within granule pair
    const int ml = lane & 15;          // swizzle key (= row&15)

    // XCD m-clustered mapping (dispatch: block b -> XCD b%8)
    const int b  = blockIdx.x;
    const int ib = b >> 3;
    const int m0 = ((b & 7) * 4 + (ib >> 4)) * BM;
    const int n0 = (ib & 15) * BN;

    const int r4   = lane >> 4;        // row within 4-row staging group
    const int slot = lane & 15;        // 16B-granule slot within 256B row

    const short* ag[8];
    const short* bg[4];
    #pragma unroll
    for (int c = 0; c < 8; ++c) {
        const int gi = c * 4 + wave;           // 0..31
        const int rl = gi * 4 + r4;            // 0..127
        ag[c] = A + (size_t)(m0 + rl) * K + (slot ^ (rl & 15)) * 8;
    }
    #pragma unroll
    for (int c = 0; c < 4; ++c) {
        const int gi = c * 4 + wave;           // 0..15
        const int rl = gi * 4 + r4;            // 0..63
        bg[c] = Bt + (size_t)(n0 + rl) * K + (slot ^ (rl & 15)) * 8;
    }

    floatx16 acc[4];                   // [mi*2+ni]
    #pragma unroll
    for (int i = 0; i < 4; ++i)
        #pragma unroll
        for (int r = 0; r < 16; ++r) acc[i][r] = 0.f;

    for (int kb = 0; kb < K; kb += BK) {
        if (kb) __syncthreads();
        #pragma unroll
        for (int c = 0; c < 8; ++c) {
            gload_lds16(ag[c], &As[(c * 4 + wave) * 512]);
            ag[c] += BK;
        }
        #pragma unroll
        for (int c = 0; c < 4; ++c) {
            gload_lds16(bg[c], &Bs[(c * 4 + wave) * 512]);
            bg[c] += BK;
        }
        __syncthreads();

        #pragma unroll
        for (int t = 0; t < 4; ++t) {              // 4 x K=16 steps (K-half)
            const int g  = kh * 8 + 2 * t + hl;    // granule 0..15
            const int go = (g ^ ml) * 8;
            short8 a0 = *(const short8*)&As[(wr * 64 +      nl) * BK + go];
            short8 a1 = *(const short8*)&As[(wr * 64 + 32 + nl) * BK + go];
            short8 b0 = *(const short8*)&Bs[(          nl) * BK + go];
            short8 b1 = *(const short8*)&Bs[(     32 + nl) * BK + go];
            acc[0] = __builtin_amdgcn_mfma_f32_32x32x16_bf16(a0, b0, acc[0], 0, 0, 0);
            acc[1] = __builtin_amdgcn_mfma_f32_32x32x16_bf16(a0, b1, acc[1], 0, 0, 0);
            acc[2] = __builtin_amdgcn_mfma_f32_32x32x16_bf16(a1, b0, acc[2], 0, 0, 0);
            acc[3] = __builtin_amdgcn_mfma_f32_32x32x16_bf16(a1, b1, acc[3], 0, 0, 0);
        }
    }

    // ---- K-half reduction through LDS, then bias + relu + store ----
    // 32x32 C/D layout: col=lane&31, row=(r&3)+8*(r>>2)+4*hl.
    __syncthreads();                       // all waves done reading As/Bs
    float* red = (float*)As;               // [2 wr][64 row][64 col] f32 = 32 KB
    if (kh) {
        #pragma unroll
        for (int mi = 0; mi < 2; ++mi)
            #pragma unroll
            for (int ni = 0; ni < 2; ++ni)
                #pragma unroll
                for (int r = 0; r < 16; ++r) {
                    const int row32 = (r & 3) + 8 * (r >> 2) + 4 * hl;
                    red[wr * 4096 + (mi * 32 + row32) * 64 + ni * 32 + nl] =
                        acc[mi * 2 + ni][r];
                }
    }
    __syncthreads();
    if (!kh) {
        const float bv0 = bias[n0 + nl];
        const float bv1 = bias[n0 + 32 + nl];
        #pragma unroll
        for (int mi = 0; mi < 2; ++mi)
            #pragma unroll
            for (int ni = 0; ni < 2; ++ni) {
                const float bv = ni ? bv1 : bv0;
                #pragma unroll
                for (int r = 0; r < 16; ++r) {
                    const int row32 = (r & 3) + 8 * (r >> 2) + 4 * hl;
                    const int gm = m0 + wr * 64 + mi * 32 + row32;
                    const int gn = n0 + ni * 32 + nl;
                    float v = acc[mi * 2 + ni][r]
                            + red[wr * 4096 + (mi * 32 + row32) * 64 + ni * 32 + nl]
                            + bv;
                    out[(size_t)gm * N + gn] = v > 0.f ? v : 0.f;
                }
            }
    }
}

// ---------------------------------------------------------------------------
extern "C" void kernel_launch(void* const* d_in, const int* in_sizes, int n_in,
                              void* d_out, int out_size, void* d_ws, size_t ws_size,
                              hipStream_t stream) {
    const float* h    = (const float*)d_in[0];   // (1, B, 64) f32
    const float* pos  = (const float*)d_in[2];   // (B, 2)     f32
    const float* W    = (const float*)d_in[4];   // (K, N)     f32
    const float* bias = (const float*)d_in[5];   // (N,)       f32

    const int B = in_sizes[0] / 64;       // 4096
    const int N = in_sizes[5];            // 1024
    const int K = 64 * 64;                // GRID^2 * H_DIM = 4096

    short* pooled = (short*)d_ws;                  // B*K bf16 = 32 MB
    short* Wt     = pooled + (size_t)B * K;        // N*K bf16 =  8 MB
    float* out    = (float*)d_out;

    const int poolBlocks = B / 4;                  // 1024
    const int castBlocks = (K / 64) * (N / 64);    // 1024
    prep_kernel<<<poolBlocks + castBlocks, 256, 0, stream>>>(
        h, pos, pooled, W, Wt, K, N, poolBlocks);
    gemm_bias_relu<<<(B / BM) * (N / BN), 256, 0, stream>>>(
        pooled, Wt, bias, out, B, N, K);
}